// Round 7
// baseline (123.635 us; speedup 1.0000x reference)
//
#include <hip/hip_runtime.h>
#include <hip/hip_bf16.h>

#define BB   16
#define CIN  256
#define COUT 256
#define WD   256
#define HH   64
#define WWS  64
#define NSP  4096      // HH*WWS
#define KW   9

typedef __attribute__((ext_vector_type(8))) short short8;
typedef __attribute__((ext_vector_type(4))) float f32x4;
typedef unsigned short ushort_t;
typedef unsigned int uint_t;

// workspace layout
#define S_BYTES (BB*CIN*4)                       // 16 KB
#define WT_OFF (S_BYTES)
#define WT_BYTES (BB*9*COUT*CIN*2)               // 18.87 MB
#define X_OFF (WT_OFF + WT_BYTES)
#define X_BYTES (BB*NSP*CIN*2)                   // 33.55 MB
#define ZP_OFF (X_OFF + X_BYTES)
#define ZP_BYTES 4096
#define WS_NEEDED ((size_t)(ZP_OFF + ZP_BYTES))

#define WAITVM0 asm volatile("s_waitcnt vmcnt(0)" ::: "memory")
#define WAITVM3 asm volatile("s_waitcnt vmcnt(3)" ::: "memory")

__device__ inline ushort_t f2bf(float f) {
    __hip_bfloat16 h = __float2bfloat16(f);
    return __builtin_bit_cast(ushort_t, h);
}

__device__ inline void gload_lds16(const ushort_t* g, ushort_t* l) {
    __builtin_amdgcn_global_load_lds(
        (const __attribute__((address_space(1))) void*)g,
        (__attribute__((address_space(3))) void*)l, 16, 0, 0);
}

// ---------------------------------------------------------------------------
// Kernel 0: zero page for OOB x rows
// ---------------------------------------------------------------------------
__global__ __launch_bounds__(256)
void zero_kernel(float* __restrict__ zp) {
    ((float4*)zp)[threadIdx.x] = make_float4(0.f, 0.f, 0.f, 0.f);
}

// ---------------------------------------------------------------------------
// Kernel 1: style modulation
// ---------------------------------------------------------------------------
__global__ __launch_bounds__(256)
void style_kernel(const float* __restrict__ w,
                  const float* __restrict__ style_w,
                  const float* __restrict__ style_b,
                  float* __restrict__ s) {
    const int b  = blockIdx.x;
    const int ci = threadIdx.x;
    __shared__ float wsh[WD];
    wsh[ci] = w[b * WD + ci];
    __syncthreads();
    const float* row = style_w + ci * WD;
    float acc = style_b[ci];
    #pragma unroll 4
    for (int k = 0; k < WD; ++k) acc += wsh[k] * row[k];
    s[b * CIN + ci] = acc;
}

// ---------------------------------------------------------------------------
// Kernel 2: demodulated weights -> bf16, layout [b][tap][co][ci]
// ---------------------------------------------------------------------------
__global__ __launch_bounds__(256)
void wt_kernel(const float* __restrict__ cw, const float* __restrict__ s,
               const float* __restrict__ scale_p, ushort_t* __restrict__ wt) {
    const int co = blockIdx.x, b = blockIdx.y, ci = threadIdx.x;
    const float sv = s[b * CIN + ci] * scale_p[0];
    const float* cp = cw + ((size_t)co * CIN + ci) * KW;
    float v[9];
    float ss = 0.f;
    #pragma unroll
    for (int t = 0; t < 9; ++t) { v[t] = cp[t] * sv; ss += v[t] * v[t]; }
    #pragma unroll
    for (int off = 32; off > 0; off >>= 1) ss += __shfl_down(ss, off);
    __shared__ float red[4];
    if ((ci & 63) == 0) red[ci >> 6] = ss;
    __syncthreads();
    const float dm = rsqrtf(red[0] + red[1] + red[2] + red[3] + 1e-8f);
    #pragma unroll
    for (int t = 0; t < 9; ++t)
        wt[((size_t)(b * 9 + t) * COUT + co) * CIN + ci] = f2bf(v[t] * dm);
}

// ---------------------------------------------------------------------------
// Kernel 3: x NCHW fp32 -> NHWC bf16  (xo[b][sp][ci])
// ---------------------------------------------------------------------------
__global__ __launch_bounds__(256)
void xpose_kernel(const float* __restrict__ x, ushort_t* __restrict__ xo) {
    const int spt = blockIdx.x;
    const int cit = blockIdx.y;
    const int b   = blockIdx.z;
    const int t   = threadIdx.x;
    __shared__ ushort_t tile[64 * 68];
    const int sp0 = spt * 64, ci0 = cit * 64;
    {
        const int spq = t & 15, cil = t >> 4;
        #pragma unroll
        for (int i = 0; i < 4; ++i) {
            const int ci = cil + i * 16;
            const float4 v = *(const float4*)(x + ((size_t)(b * CIN + ci0 + ci)) * NSP + sp0 + spq * 4);
            tile[(spq * 4 + 0) * 68 + ci] = f2bf(v.x);
            tile[(spq * 4 + 1) * 68 + ci] = f2bf(v.y);
            tile[(spq * 4 + 2) * 68 + ci] = f2bf(v.z);
            tile[(spq * 4 + 3) * 68 + ci] = f2bf(v.w);
        }
    }
    __syncthreads();
    {
        const int g4 = t & 15, sp = t >> 4;
        #pragma unroll
        for (int i = 0; i < 4; ++i) {
            const int spp = sp + i * 16;
            uint2 v = *(const uint2*)&tile[spp * 68 + g4 * 4];
            *(uint2*)(xo + ((size_t)(b * NSP + sp0 + spp)) * CIN + ci0 + g4 * 4) = v;
        }
    }
}

// ---------------------------------------------------------------------------
// Kernel 4: implicit-GEMM conv, granule-3 schedule (barriers 72 -> 24).
//   256 blocks (16 b x 16 ntile, 1/CU), 512 threads = 8 waves (4M x 2N).
//   Block tile 256 co x 256 sp; wave tile 64x128 -> acc[4][8].
//   Granule = 3 taps (one ky row). Per granule: 1 barrier; A granule
//   (3x256x32 bf16 = 48 KB) double-buffered via global_load_lds, 1-ahead;
//   x [2][6][66][32] dbuf, issued at mid-granule of previous chunk.
//   Within granule: frag reads for tap t+1 overlap MFMA of tap t
//   (explicit 2-set rotation; compiler emits fine-grained lgkmcnt).
//   Waits: vmcnt(3) at gph==2 (preserve x), vmcnt(0) elsewhere (exact).
// ---------------------------------------------------------------------------
__global__ __launch_bounds__(512, 2)
void conv_mfma_kernel(const ushort_t* __restrict__ wt,   // [b][9][256][256]
                      const ushort_t* __restrict__ xo,   // [b][4096][256]
                      const ushort_t* __restrict__ zp,   // zero page
                      float* __restrict__ out) {
    const int wg    = blockIdx.x;              // 0..255
    const int b     = wg & 15;                 // XCD k gets b in {k, k+8}
    const int ntile = wg >> 4;                 // 0..15
    const int y0    = ntile * 4;

    const int tid  = threadIdx.x;
    const int lane = tid & 63;
    const int w    = tid >> 6;                 // wave 0..7
    const int wm   = w >> 1;                   // co quarter (4M)
    const int wn   = w & 1;                    // spatial half (2N)
    const int l15  = lane & 15;
    const int lg   = lane >> 4;

    __shared__ __align__(16) ushort_t lds_a[2 * 3 * 256 * 32];   // 98304 B
    __shared__ __align__(16) ushort_t lds_x[2 * 6 * 66 * 32];    // 50688 B

    // ---- DMA source quad swizzle (uniform involution key) ----
    const int keyW  = ((lane >> 2) ^ (lane >> 4)) & 3;
    const uint_t srcq8 = (uint_t)(((lane & 3) ^ keyW) * 8);

    // A: 6 calls/granule. cell i*512+tid: tap_g=i>>1, row=(i&1)*128+(tid>>2)
    const uint_t wtb    = (uint_t)b * 9u * COUT * CIN;
    const uint_t a_src0 = (uint_t)(tid >> 2) * 256u + srcq8;
    const int    tid8   = tid * 8;

    // x: 3 calls/chunk. cell j*512+tid: r=2j+hi, col=(tid>>2)&63
    const int hi  = tid >> 8;
    const int col = (tid >> 2) & 63;
    const int xdb = hi * 2112 + (col + 1) * 32 + (lane & 3) * 8;
    const ushort_t* px[3];
    #pragma unroll
    for (int j = 0; j < 3; ++j) {
        const int y = y0 - 1 + hi + 2 * j;
        px[j] = (y >= 0 && y < HH)
              ? (xo + (uint_t)b * (NSP * CIN) + (uint_t)(y * WWS + col) * CIN + srcq8)
              : (zp + lane * 8);               // zp big enough for +cs*32
    }

    // ---- fragment read slot swizzles ----
    const int slotA8 = (lg ^ ((l15 ^ (l15 >> 2)) & 3)) * 8;
    int slotB8[3];
    #pragma unroll
    for (int kx = 0; kx < 3; ++kx) {
        int c2 = l15 + kx - 1;
        if (c2 < 0) c2 = 0;
        slotB8[kx] = (lg ^ ((c2 ^ (c2 >> 2)) & 3)) * 8;
    }
    const int abase = (wm * 64 + l15) * 32 + slotA8;

    f32x4 acc[4][8];
    #pragma unroll
    for (int mi = 0; mi < 4; ++mi)
        #pragma unroll
        for (int ni = 0; ni < 8; ++ni) acc[mi][ni] = (f32x4){0.f, 0.f, 0.f, 0.f};

    // ---- zero halo columns (cols 0 and 65) of both x buffers, once ----
    if (tid < 96) {
        const int cell = tid >> 2, qq = tid & 3;
        const int buf = cell / 12, cr = cell % 12;
        const int r = cr >> 1, hc = (cr & 1) * 65;
        *(uint4*)&lds_x[buf * 12672 + r * 2112 + hc * 32 + qq * 8] =
            make_uint4(0, 0, 0, 0);
    }
    asm volatile("s_waitcnt lgkmcnt(0)" ::: "memory");
    __builtin_amdgcn_sched_barrier(0);

    #define ISSUE_A(TB, CHN, DSTSEL)                                           \
    {   ushort_t* adst_ = lds_a + (DSTSEL) * 24576;                            \
        _Pragma("unroll")                                                      \
        for (int i_ = 0; i_ < 6; ++i_)                                         \
            gload_lds16(wt + (wtb + (uint_t)((TB) + (i_ >> 1)) * 65536u        \
                              + (uint_t)(CHN) * 32u + a_src0                   \
                              + (uint_t)(i_ & 1) * 32768u),                    \
                        adst_ + tid8 + i_ * 4096);                             \
    }
    #define ISSUE_X(CS, DSTSEL)                                                \
    {   ushort_t* xdst_ = lds_x + (DSTSEL) * 12672;                            \
        _Pragma("unroll")                                                      \
        for (int j_ = 0; j_ < 3; ++j_)                                         \
            gload_lds16(px[j_] + (CS) * 32, xdst_ + xdb + j_ * 4224);          \
    }
    #define READF(AF, BF, TG)                                                  \
    {   _Pragma("unroll")                                                      \
        for (int mi_ = 0; mi_ < 4; ++mi_)                                      \
            AF[mi_] = *(const short8*)(ab + (TG) * 8192 + mi_ * 512);          \
        _Pragma("unroll")                                                      \
        for (int ni_ = 0; ni_ < 8; ++ni_)                                      \
            BF[ni_] = *(const short8*)(xb + (xrow + (ni_ >> 2)) * 2112         \
                        + ((ni_ & 3) * 16 + l15 + (TG)) * 32 + slotB8[TG]);    \
    }
    #define MFMAC(AF, BF)                                                      \
    {   __builtin_amdgcn_s_setprio(1);                                         \
        _Pragma("unroll")                                                      \
        for (int mi_ = 0; mi_ < 4; ++mi_)                                      \
            _Pragma("unroll")                                                  \
            for (int ni_ = 0; ni_ < 8; ++ni_)                                  \
                acc[mi_][ni_] = __builtin_amdgcn_mfma_f32_16x16x32_bf16(       \
                    BF[ni_], AF[mi_], acc[mi_][ni_], 0, 0, 0);                 \
        __builtin_amdgcn_s_setprio(0);                                         \
    }

    // ---- prologue: x(chunk0) then A(granule0) -> buf0 ----
    ISSUE_X(0, 0);
    ISSUE_A(0, 0, 0);

    #pragma unroll 1
    for (int chunk = 0; chunk < 8; ++chunk) {
        #pragma unroll
        for (int gph = 0; gph < 3; ++gph) {
            if (gph == 2 && chunk != 7) { WAITVM3; } else { WAITVM0; }
            __builtin_amdgcn_sched_barrier(0);
            __builtin_amdgcn_s_barrier();
            __builtin_amdgcn_sched_barrier(0);

            const int Gpar = (chunk ^ gph) & 1;          // (chunk*3+gph)&1
            // issue A for next granule (1-ahead), skip at very last granule
            if (!(chunk == 7 && gph == 2)) {
                const int tb2 = ((gph + 1) % 3) * 3;
                const int chn = chunk + (gph == 2 ? 1 : 0);
                ISSUE_A(tb2, chn, Gpar ^ 1);
            }
            // issue x for next chunk at mid-granule
            if (gph == 1 && chunk < 7) ISSUE_X(chunk + 1, (chunk + 1) & 1);

            const ushort_t* ab = lds_a + Gpar * 24576 + abase;
            const ushort_t* xb = lds_x + (chunk & 1) * 12672;
            const int xrow = wn * 2 + gph;               // + (ni>>2)

            short8 af0[4], bf0[8], af1[4], bf1[8];
            READF(af0, bf0, 0);
            READF(af1, bf1, 1);
            MFMAC(af0, bf0);
            READF(af0, bf0, 2);
            MFMAC(af1, bf1);
            MFMAC(af0, bf0);
        }
    }

    // ---- epilogue: D col = co = l15, rows = sp -> f32x4 stores ----
    #pragma unroll
    for (int mi = 0; mi < 4; ++mi) {
        const int co = wm * 64 + mi * 16 + l15;
        float* ob = out + ((long)(b * COUT + co)) * NSP
                  + ntile * 256 + wn * 128 + lg * 4;
        #pragma unroll
        for (int ni = 0; ni < 8; ++ni)
            *(f32x4*)(ob + ni * 16) = acc[mi][ni];
    }
    #undef ISSUE_A
    #undef ISSUE_X
    #undef READF
    #undef MFMAC
}

// ---------------------------------------------------------------------------
// Fallback fp32 direct conv if workspace is too small.
// ---------------------------------------------------------------------------
__global__ __launch_bounds__(256)
void modconv_kernel(const float* __restrict__ x,
                    const float* __restrict__ cw,
                    const float* __restrict__ s,
                    const float* __restrict__ scale_p,
                    float* __restrict__ out) {
    const int tile = blockIdx.x;
    const int co   = blockIdx.y;
    const int b    = blockIdx.z;
    const int tid  = threadIdx.x;
    const float scale = scale_p[0];

    __shared__ float s_wt[CIN * KW];
    __shared__ float s_x[18 * 66];
    __shared__ float red[4];

    const float* cwb = cw + (size_t)co * CIN * KW;
    const float* sb  = s + b * CIN;
    float sumsq = 0.f;
    for (int i = tid; i < CIN * KW; i += 256) {
        float v = cwb[i] * scale * sb[i / KW];
        s_wt[i] = v;
        sumsq += v * v;
    }
    #pragma unroll
    for (int off = 32; off > 0; off >>= 1) sumsq += __shfl_down(sumsq, off);
    if ((tid & 63) == 0) red[tid >> 6] = sumsq;
    __syncthreads();
    const float demod = rsqrtf(red[0] + red[1] + red[2] + red[3] + 1e-8f);
    for (int i = tid; i < CIN * KW; i += 256) s_wt[i] *= demod;

    const int tx = tid & 63;
    const int tr = tid >> 6;
    const int y0 = tile * 16;
    float acc[4] = {0.f, 0.f, 0.f, 0.f};

    for (int ci = 0; ci < CIN; ++ci) {
        __syncthreads();
        const float* xb = x + ((size_t)(b * CIN + ci)) * (HH * WWS);
        for (int idx = tid; idx < 18 * 66; idx += 256) {
            const int r = idx / 66, c = idx % 66;
            const int yg = y0 - 1 + r, xg = c - 1;
            float v = 0.f;
            if (yg >= 0 && yg < HH && xg >= 0 && xg < WWS) v = xb[yg * WWS + xg];
            s_x[idx] = v;
        }
        __syncthreads();
        const float* wr = s_wt + ci * KW;
        const float w0 = wr[0], w1 = wr[1], w2 = wr[2];
        const float w3 = wr[3], w4 = wr[4], w5 = wr[5];
        const float w6 = wr[6], w7 = wr[7], w8 = wr[8];
        const int rbase = tr * 4;
        float xv[6][3];
        #pragma unroll
        for (int j = 0; j < 6; ++j)
            #pragma unroll
            for (int k = 0; k < 3; ++k) xv[j][k] = s_x[(rbase + j) * 66 + tx + k];
        #pragma unroll
        for (int i = 0; i < 4; ++i)
            acc[i] += w0 * xv[i][0] + w1 * xv[i][1] + w2 * xv[i][2]
                    + w3 * xv[i+1][0] + w4 * xv[i+1][1] + w5 * xv[i+1][2]
                    + w6 * xv[i+2][0] + w7 * xv[i+2][1] + w8 * xv[i+2][2];
    }
    float* ob = out + (((size_t)(b * COUT + co)) * HH + y0) * WWS + tx;
    #pragma unroll
    for (int i = 0; i < 4; ++i) ob[(tr * 4 + i) * WWS] = acc[i];
}

// ---------------------------------------------------------------------------
extern "C" void kernel_launch(void* const* d_in, const int* in_sizes, int n_in,
                              void* d_out, int out_size, void* d_ws, size_t ws_size,
                              hipStream_t stream) {
    const float* x       = (const float*)d_in[0];
    const float* w       = (const float*)d_in[1];
    const float* cw      = (const float*)d_in[2];
    const float* style_w = (const float*)d_in[3];
    const float* style_b = (const float*)d_in[4];
    const float* scale_p = (const float*)d_in[5];
    float*       out     = (float*)d_out;

    float*    s    = (float*)d_ws;
    ushort_t* wswt = (ushort_t*)((char*)d_ws + WT_OFF);
    ushort_t* wsx  = (ushort_t*)((char*)d_ws + X_OFF);
    float*    zp   = (float*)((char*)d_ws + ZP_OFF);

    style_kernel<<<dim3(BB), 256, 0, stream>>>(w, style_w, style_b, s);

    if (ws_size >= WS_NEEDED) {
        zero_kernel<<<dim3(1), 256, 0, stream>>>(zp);
        wt_kernel<<<dim3(COUT, BB), 256, 0, stream>>>(cw, s, scale_p, wswt);
        xpose_kernel<<<dim3(64, 4, BB), 256, 0, stream>>>(x, wsx);
        conv_mfma_kernel<<<dim3(256), 512, 0, stream>>>(wswt, wsx,
                                                        (const ushort_t*)zp, out);
    } else {
        modconv_kernel<<<dim3(4, COUT, BB), 256, 0, stream>>>(x, cw, s, scale_p, out);
    }
}

// Round 8
// 112.449 us; speedup vs baseline: 1.0995x; 1.0995x over previous
//
#include <hip/hip_runtime.h>
#include <hip/hip_bf16.h>

#define BB   16
#define CIN  256
#define COUT 256
#define WD   256
#define HH   64
#define WWS  64
#define NSP  4096      // HH*WWS
#define KW   9

typedef __attribute__((ext_vector_type(8))) short short8;
typedef __attribute__((ext_vector_type(4))) float f32x4;
typedef unsigned short ushort_t;
typedef unsigned int uint_t;

// workspace layout
#define S_BYTES (BB*CIN*4)                       // 16 KB
#define WT_OFF (S_BYTES)
#define WT_BYTES (BB*9*COUT*CIN*2)               // 18.87 MB
#define X_OFF (WT_OFF + WT_BYTES)
#define X_BYTES (BB*NSP*CIN*2)                   // 33.55 MB
#define ZP_OFF (X_OFF + X_BYTES)
#define ZP_BYTES 4096
#define WS_NEEDED ((size_t)(ZP_OFF + ZP_BYTES))

#define WAITVM4 asm volatile("s_waitcnt vmcnt(4)" ::: "memory")
#define WAITVM7 asm volatile("s_waitcnt vmcnt(7)" ::: "memory")

__device__ inline ushort_t f2bf(float f) {
    __hip_bfloat16 h = __float2bfloat16(f);
    return __builtin_bit_cast(ushort_t, h);
}

__device__ inline void gload_lds16(const ushort_t* g, ushort_t* l) {
    __builtin_amdgcn_global_load_lds(
        (const __attribute__((address_space(1))) void*)g,
        (__attribute__((address_space(3))) void*)l, 16, 0, 0);
}

// ---------------------------------------------------------------------------
// Kernel 1: style modulation
// ---------------------------------------------------------------------------
__global__ __launch_bounds__(256)
void style_kernel(const float* __restrict__ w,
                  const float* __restrict__ style_w,
                  const float* __restrict__ style_b,
                  float* __restrict__ s) {
    const int b  = blockIdx.x;
    const int ci = threadIdx.x;
    __shared__ float wsh[WD];
    wsh[ci] = w[b * WD + ci];
    __syncthreads();
    const float* row = style_w + ci * WD;
    float acc = style_b[ci];
    #pragma unroll 4
    for (int k = 0; k < WD; ++k) acc += wsh[k] * row[k];
    s[b * CIN + ci] = acc;
}

// ---------------------------------------------------------------------------
// Kernel 2: demodulated weights -> bf16, layout [b][tap][co][ci]
//           (block (0,0) also zero-fills the zp page used by conv)
// ---------------------------------------------------------------------------
__global__ __launch_bounds__(256)
void wt_kernel(const float* __restrict__ cw, const float* __restrict__ s,
               const float* __restrict__ scale_p, ushort_t* __restrict__ wt,
               float* __restrict__ zp) {
    const int co = blockIdx.x, b = blockIdx.y, ci = threadIdx.x;
    if (co == 0 && b == 0)
        ((float4*)zp)[ci] = make_float4(0.f, 0.f, 0.f, 0.f);
    const float sv = s[b * CIN + ci] * scale_p[0];
    const float* cp = cw + ((size_t)co * CIN + ci) * KW;
    float v[9];
    float ss = 0.f;
    #pragma unroll
    for (int t = 0; t < 9; ++t) { v[t] = cp[t] * sv; ss += v[t] * v[t]; }
    #pragma unroll
    for (int off = 32; off > 0; off >>= 1) ss += __shfl_down(ss, off);
    __shared__ float red[4];
    if ((ci & 63) == 0) red[ci >> 6] = ss;
    __syncthreads();
    const float dm = rsqrtf(red[0] + red[1] + red[2] + red[3] + 1e-8f);
    #pragma unroll
    for (int t = 0; t < 9; ++t)
        wt[((size_t)(b * 9 + t) * COUT + co) * CIN + ci] = f2bf(v[t] * dm);
}

// ---------------------------------------------------------------------------
// Kernel 3: x NCHW fp32 -> NHWC bf16  (xo[b][sp][ci]); uint4 stores
// ---------------------------------------------------------------------------
__global__ __launch_bounds__(256)
void xpose_kernel(const float* __restrict__ x, ushort_t* __restrict__ xo) {
    const int spt = blockIdx.x;
    const int cit = blockIdx.y;
    const int b   = blockIdx.z;
    const int t   = threadIdx.x;
    __shared__ ushort_t tile[64 * 72];
    const int sp0 = spt * 64, ci0 = cit * 64;
    {
        const int spq = t & 15, cil = t >> 4;
        #pragma unroll
        for (int i = 0; i < 4; ++i) {
            const int ci = cil + i * 16;
            const float4 v = *(const float4*)(x + ((size_t)(b * CIN + ci0 + ci)) * NSP + sp0 + spq * 4);
            tile[(spq * 4 + 0) * 72 + ci] = f2bf(v.x);
            tile[(spq * 4 + 1) * 72 + ci] = f2bf(v.y);
            tile[(spq * 4 + 2) * 72 + ci] = f2bf(v.z);
            tile[(spq * 4 + 3) * 72 + ci] = f2bf(v.w);
        }
    }
    __syncthreads();
    {
        const int g8 = t & 7, sp = t >> 3;     // sp 0..31
        #pragma unroll
        for (int i = 0; i < 2; ++i) {
            const int spp = sp + i * 32;
            uint4 v = *(const uint4*)&tile[spp * 72 + g8 * 8];
            *(uint4*)(xo + ((size_t)(b * NSP + sp0 + spp)) * CIN + ci0 + g8 * 8) = v;
        }
    }
}

// ---------------------------------------------------------------------------
// Kernel 4: implicit-GEMM conv, barrier-free K-loop via per-wave A panels.
//   256 blocks (16 b x 16 ntile), 512 threads = 8 waves (4M x 2N).
//   Block tile 256 co x 256 sp; wave tile 64x128 -> acc[4][8].
//   A: per-wave PRIVATE [3][64][32] triple-buffer, staged by the wave's own
//      global_load_lds (4 calls/tap, 2-ahead) and synced with the wave's own
//      counted vmcnt(4/7) -- NO block barrier in the tap loop. Waves desync.
//   x: shared [2][6][66][32] dbuf; each wave's 3 calls issued at tap 4,
//      own-forced by tap-6's vmcnt(4); ONE barrier per chunk for visibility.
//   Frags for tap t+1 are ds_read (double register set, compile-time parity
//   via 2-chunk-unrolled bodies) while MFMA(t) executes.
// ---------------------------------------------------------------------------
__global__ __launch_bounds__(512, 2)
void conv_mfma_kernel(const ushort_t* __restrict__ wt,   // [b][9][256][256]
                      const ushort_t* __restrict__ xo,   // [b][4096][256]
                      const ushort_t* __restrict__ zp,   // zero page
                      float* __restrict__ out) {
    const int wg    = blockIdx.x;              // 0..255
    const int b     = (wg & 7) | (((wg >> 3) & 1) << 3);  // batch per XCD
    const int ntile = wg >> 4;                 // 0..15
    const int y0    = ntile * 4;

    const int tid  = threadIdx.x;
    const int lane = tid & 63;
    const int w    = tid >> 6;                 // wave 0..7
    const int wm   = w >> 1;                   // co quarter
    const int wn   = w & 1;                    // spatial half (2 rows)
    const int wn2  = wn * 2;
    const int l15  = lane & 15;
    const int lg   = lane >> 4;
    const int lane8 = lane * 8;

    __shared__ __align__(16) ushort_t lds_a[8 * 3 * 2048];   // 98304 B
    __shared__ __align__(16) ushort_t lds_x[2 * 6 * 66 * 32];// 50688 B

    // ---- DMA source quad swizzle (involution, key = f(row/col)) ----
    const uint_t srcq8 = (uint_t)(((lane & 3) ^ (((lane >> 2) ^ (lane >> 4)) & 3)) * 8);

    // A: own 64-co slice, 4 calls/tap (call i: rows i*16 + lane>>2)
    const ushort_t* pa = wt + (size_t)b * (9 * COUT * CIN)
                       + (uint_t)(wm * 64 + (lane >> 2)) * CIN + srcq8;
    const int awbase = w * 6144;               // per-wave LDS region (ushorts)

    // x: 3 calls/chunk. cell = w*3+j: row = cell>>2, colgroup = cell&3
    const ushort_t* px[3];
    int xdst_off[3];
    #pragma unroll
    for (int j = 0; j < 3; ++j) {
        const int cell = w * 3 + j;
        const int r    = cell >> 2;
        const int cg   = cell & 3;
        const int col  = cg * 16 + (lane >> 2);
        const int y    = y0 - 1 + r;
        const bool val = (y >= 0 && y < HH);
        px[j] = val ? (xo + (size_t)b * (NSP * CIN) + (uint_t)(y * WWS + col) * CIN + srcq8)
                    : (zp + lane8);
        xdst_off[j] = r * 2112 + (cg * 16 + 1) * 32 + lane8;
    }

    // ---- fragment read slot swizzles ----
    const int slotA8 = (lg ^ ((l15 ^ (l15 >> 2)) & 3)) * 8;
    int slotB8[3];
    #pragma unroll
    for (int kx = 0; kx < 3; ++kx) {
        int c2 = l15 + kx - 1;
        if (c2 < 0) c2 = 0;                    // halo col: zeros, any slot
        slotB8[kx] = (lg ^ ((c2 ^ (c2 >> 2)) & 3)) * 8;
    }
    const int ardbase = l15 * 32 + slotA8;     // + mi*512 within wave A buf

    f32x4 acc[4][8];
    #pragma unroll
    for (int mi = 0; mi < 4; ++mi)
        #pragma unroll
        for (int ni = 0; ni < 8; ++ni) acc[mi][ni] = (f32x4){0.f, 0.f, 0.f, 0.f};

    short8 af[2][4], bf[2][8];

    // ---- zero halo cols (0 and 65) of both x buffers, once ----
    if (tid < 96) {
        const int cell = tid >> 2, qq = tid & 3;
        const int buf = cell / 12, cr = cell % 12;
        const int r = cr >> 1, hc = (cr & 1) * 65;
        *(uint4*)&lds_x[buf * 12672 + r * 2112 + hc * 32 + qq * 8] =
            make_uint4(0, 0, 0, 0);
    }

    // ---- prologue: x(c0)[3], A(T0)->buf0 [4], A(T1)->buf1 [4] ----
    #pragma unroll
    for (int j = 0; j < 3; ++j)
        gload_lds16(px[j], lds_x + xdst_off[j]);
    #pragma unroll
    for (int i = 0; i < 4; ++i)
        gload_lds16(pa + i * 4096, lds_a + awbase + i * 512 + lane8);
    #pragma unroll
    for (int i = 0; i < 4; ++i)
        gload_lds16(pa + 65536 + i * 4096, lds_a + awbase + 2048 + i * 512 + lane8);

    WAITVM4;                                   // x + A(T0) done (A(T1) in flight)
    asm volatile("s_waitcnt lgkmcnt(0)" ::: "memory");
    __builtin_amdgcn_sched_barrier(0);
    __builtin_amdgcn_s_barrier();              // all waves' x visible

    // read frags(T0) -> set 0
    {
        const ushort_t* ar = lds_a + awbase + ardbase;
        #pragma unroll
        for (int mi = 0; mi < 4; ++mi) af[0][mi] = *(const short8*)(ar + mi * 512);
        #pragma unroll
        for (int ni = 0; ni < 8; ++ni)
            bf[0][ni] = *(const short8*)(lds_x + (wn2 + (ni >> 2)) * 2112
                          + ((ni & 3) * 16 + l15) * 32 + slotB8[0]);
    }

    #define TAP(t, CP, cvar)                                                   \
    {                                                                          \
        constexpr int P_ = ((CP) + (t)) & 1;                                   \
        constexpr int Q_ = P_ ^ 1;                                             \
        /* issue A(T+2) -> buf (t+2)%3 (dummy wrap at tail) */                 \
        {                                                                      \
            constexpr int tp2 = ((t) + 2) % 9;                                 \
            constexpr int bA  = ((t) + 2) % 3;                                 \
            const int ch2 = ((cvar) + (((t) + 2) / 9)) & 7;                    \
            const uint_t aoff = (uint_t)tp2 * 65536u + (uint_t)ch2 * 32u;      \
            ushort_t* ad = lds_a + awbase + bA * 2048 + lane8;                 \
            _Pragma("unroll")                                                  \
            for (int i_ = 0; i_ < 4; ++i_)                                     \
                gload_lds16(pa + aoff + i_ * 4096, ad + i_ * 512);             \
        }                                                                      \
        if ((t) == 4) {  /* x(c+1), dummy wrap at c==7 */                      \
            const int cs = ((cvar) + 1) & 7;                                   \
            ushort_t* xd = lds_x + ((CP) ^ 1) * 12672;                         \
            _Pragma("unroll")                                                  \
            for (int j_ = 0; j_ < 3; ++j_)                                     \
                gload_lds16(px[j_] + cs * 32, xd + xdst_off[j_]);              \
        }                                                                      \
        /* counted wait: A(t+1) arrived (own-wave vmcnt, no barrier) */        \
        if ((t) == 4 || (t) == 5) { WAITVM7; } else { WAITVM4; }               \
        __builtin_amdgcn_sched_barrier(0);                                     \
        /* read frags for T+1 into set Q (overlaps MFMA below) */              \
        {                                                                      \
            constexpr int bA1 = ((t) + 1) % 3;                                 \
            const ushort_t* ar = lds_a + awbase + bA1 * 2048 + ardbase;        \
            _Pragma("unroll")                                                  \
            for (int mi_ = 0; mi_ < 4; ++mi_)                                  \
                af[Q_][mi_] = *(const short8*)(ar + mi_ * 512);                \
        }                                                                      \
        if ((t) < 8) {                                                         \
            constexpr int t1_ = (t) + 1;                                       \
            constexpr int ky_ = t1_ / 3, kx_ = t1_ % 3;                        \
            const ushort_t* xr = lds_x + (CP) * 12672;                         \
            _Pragma("unroll")                                                  \
            for (int ni_ = 0; ni_ < 8; ++ni_)                                  \
                bf[Q_][ni_] = *(const short8*)(xr                              \
                    + (wn2 + (ni_ >> 2) + ky_) * 2112                          \
                    + ((ni_ & 3) * 16 + l15 + kx_) * 32 + slotB8[kx_]);        \
        }                                                                      \
        __builtin_amdgcn_s_setprio(1);                                         \
        _Pragma("unroll")                                                      \
        for (int mi_ = 0; mi_ < 4; ++mi_)                                      \
            _Pragma("unroll")                                                  \
            for (int ni_ = 0; ni_ < 8; ++ni_)                                  \
                acc[mi_][ni_] = __builtin_amdgcn_mfma_f32_16x16x32_bf16(       \
                    bf[P_][ni_], af[P_][mi_], acc[mi_][ni_], 0, 0, 0);         \
        __builtin_amdgcn_s_setprio(0);                                         \
        __builtin_amdgcn_sched_barrier(0);                                     \
    }

    #define CHUNK_TAIL(CP, cvar)                                               \
    {                                                                          \
        __builtin_amdgcn_s_barrier();   /* x(c+1) visible (tap6 forced own) */ \
        constexpr int Q_ = ((CP) + 9) & 1;                                     \
        const ushort_t* xr = lds_x + ((CP) ^ 1) * 12672;                       \
        _Pragma("unroll")                                                      \
        for (int ni_ = 0; ni_ < 8; ++ni_)                                      \
            bf[Q_][ni_] = *(const short8*)(xr + (wn2 + (ni_ >> 2)) * 2112      \
                + ((ni_ & 3) * 16 + l15) * 32 + slotB8[0]);                    \
    }

    #pragma unroll 1
    for (int c2 = 0; c2 < 4; ++c2) {
        const int ce = c2 * 2, cd = ce + 1;
        TAP(0, 0, ce) TAP(1, 0, ce) TAP(2, 0, ce) TAP(3, 0, ce) TAP(4, 0, ce)
        TAP(5, 0, ce) TAP(6, 0, ce) TAP(7, 0, ce) TAP(8, 0, ce)
        CHUNK_TAIL(0, ce)
        TAP(0, 1, cd) TAP(1, 1, cd) TAP(2, 1, cd) TAP(3, 1, cd) TAP(4, 1, cd)
        TAP(5, 1, cd) TAP(6, 1, cd) TAP(7, 1, cd) TAP(8, 1, cd)
        CHUNK_TAIL(1, cd)
    }
    #undef TAP
    #undef CHUNK_TAIL

    // drain outstanding (dummy) DMAs before LDS dealloc / epilogue
    asm volatile("s_waitcnt vmcnt(0) lgkmcnt(0)" ::: "memory");
    __builtin_amdgcn_sched_barrier(0);

    // ---- epilogue: D col = co = l15, rows = sp -> f32x4 stores ----
    #pragma unroll
    for (int mi = 0; mi < 4; ++mi) {
        const int co = wm * 64 + mi * 16 + l15;
        float* ob = out + ((size_t)(b * COUT + co)) * NSP
                  + ntile * 256 + wn * 128 + lg * 4;
        #pragma unroll
        for (int ni = 0; ni < 8; ++ni)
            *(f32x4*)(ob + (ni >> 2) * 64 + (ni & 3) * 16) = acc[mi][ni];
    }
}

// ---------------------------------------------------------------------------
// Fallback fp32 direct conv if workspace is too small.
// ---------------------------------------------------------------------------
__global__ __launch_bounds__(256)
void modconv_kernel(const float* __restrict__ x,
                    const float* __restrict__ cw,
                    const float* __restrict__ s,
                    const float* __restrict__ scale_p,
                    float* __restrict__ out) {
    const int tile = blockIdx.x;
    const int co   = blockIdx.y;
    const int b    = blockIdx.z;
    const int tid  = threadIdx.x;
    const float scale = scale_p[0];

    __shared__ float s_wt[CIN * KW];
    __shared__ float s_x[18 * 66];
    __shared__ float red[4];

    const float* cwb = cw + (size_t)co * CIN * KW;
    const float* sb  = s + b * CIN;
    float sumsq = 0.f;
    for (int i = tid; i < CIN * KW; i += 256) {
        float v = cwb[i] * scale * sb[i / KW];
        s_wt[i] = v;
        sumsq += v * v;
    }
    #pragma unroll
    for (int off = 32; off > 0; off >>= 1) sumsq += __shfl_down(sumsq, off);
    if ((tid & 63) == 0) red[tid >> 6] = sumsq;
    __syncthreads();
    const float demod = rsqrtf(red[0] + red[1] + red[2] + red[3] + 1e-8f);
    for (int i = tid; i < CIN * KW; i += 256) s_wt[i] *= demod;

    const int tx = tid & 63;
    const int tr = tid >> 6;
    const int y0 = tile * 16;
    float acc[4] = {0.f, 0.f, 0.f, 0.f};

    for (int ci = 0; ci < CIN; ++ci) {
        __syncthreads();
        const float* xb = x + ((size_t)(b * CIN + ci)) * (HH * WWS);
        for (int idx = tid; idx < 18 * 66; idx += 256) {
            const int r = idx / 66, c = idx % 66;
            const int yg = y0 - 1 + r, xg = c - 1;
            float v = 0.f;
            if (yg >= 0 && yg < HH && xg >= 0 && xg < WWS) v = xb[yg * WWS + xg];
            s_x[idx] = v;
        }
        __syncthreads();
        const float* wr = s_wt + ci * KW;
        const float w0 = wr[0], w1 = wr[1], w2 = wr[2];
        const float w3 = wr[3], w4 = wr[4], w5 = wr[5];
        const float w6 = wr[6], w7 = wr[7], w8 = wr[8];
        const int rbase = tr * 4;
        float xv[6][3];
        #pragma unroll
        for (int j = 0; j < 6; ++j)
            #pragma unroll
            for (int k = 0; k < 3; ++k) xv[j][k] = s_x[(rbase + j) * 66 + tx + k];
        #pragma unroll
        for (int i = 0; i < 4; ++i)
            acc[i] += w0 * xv[i][0] + w1 * xv[i][1] + w2 * xv[i][2]
                    + w3 * xv[i+1][0] + w4 * xv[i+1][1] + w5 * xv[i+1][2]
                    + w6 * xv[i+2][0] + w7 * xv[i+2][1] + w8 * xv[i+2][2];
    }
    float* ob = out + (((size_t)(b * COUT + co)) * HH + y0) * WWS + tx;
    #pragma unroll
    for (int i = 0; i < 4; ++i) ob[(tr * 4 + i) * WWS] = acc[i];
}

// ---------------------------------------------------------------------------
extern "C" void kernel_launch(void* const* d_in, const int* in_sizes, int n_in,
                              void* d_out, int out_size, void* d_ws, size_t ws_size,
                              hipStream_t stream) {
    const float* x       = (const float*)d_in[0];
    const float* w       = (const float*)d_in[1];
    const float* cw      = (const float*)d_in[2];
    const float* style_w = (const float*)d_in[3];
    const float* style_b = (const float*)d_in[4];
    const float* scale_p = (const float*)d_in[5];
    float*       out     = (float*)d_out;

    float*    s    = (float*)d_ws;
    ushort_t* wswt = (ushort_t*)((char*)d_ws + WT_OFF);
    ushort_t* wsx  = (ushort_t*)((char*)d_ws + X_OFF);
    float*    zp   = (float*)((char*)d_ws + ZP_OFF);

    style_kernel<<<dim3(BB), 256, 0, stream>>>(w, style_w, style_b, s);

    if (ws_size >= WS_NEEDED) {
        wt_kernel<<<dim3(COUT, BB), 256, 0, stream>>>(cw, s, scale_p, wswt, zp);
        xpose_kernel<<<dim3(64, 4, BB), 256, 0, stream>>>(x, wsx);
        conv_mfma_kernel<<<dim3(256), 512, 0, stream>>>(wswt, wsx,
                                                        (const ushort_t*)zp, out);
    } else {
        modconv_kernel<<<dim3(4, COUT, BB), 256, 0, stream>>>(x, cw, s, scale_p, out);
    }
}